// Round 19
// baseline (370.076 us; speedup 1.0000x reference)
//
#include <hip/hip_runtime.h>
#include <hip/hip_bf16.h>
#include <math.h>

#define BB 8
#define NN 128
#define HH 128
#define NHD 4
#define DHD 32
#define LAY 4
#define EPSV 1e-5f

typedef __hip_bfloat16 bf16;
typedef unsigned short ushortt;
typedef short bf16x8 __attribute__((ext_vector_type(8)));
typedef float f32x4 __attribute__((ext_vector_type(4)));

__device__ __forceinline__ float b2f(bf16 x){ return __bfloat162float(x); }
__device__ __forceinline__ bf16 f2b(float x){ return __float2bfloat16(x); }
__device__ __forceinline__ float us2f(ushortt u){ return __uint_as_float(((unsigned)u)<<16); }
__device__ __forceinline__ ushortt f2us(float x){ bf16 b=__float2bfloat16(x); return *(ushortt*)&b; }
__device__ __forceinline__ float gelu_f(float x){ return 0.5f*x*(1.0f+erff(x*0.7071067811865476f)); }
// fast tanh-gelu — h-path serial loops only (k_edge); measured win there
__device__ __forceinline__ float gelu_h(float x){
  float t = 0.7978845608028654f*x*(1.0f + 0.044715f*x*x);
  float e = __expf(2.0f*t);
  float th = 1.0f - 2.0f/(e + 1.0f);
  return 0.5f*x*(1.0f + th);
}
// branch-free A&S 7.1.26 erf (|err| <= 1.5e-7)
__device__ __forceinline__ float erf_fast(float x){
  float ax = fabsf(x);
  float t = __builtin_amdgcn_rcpf(__builtin_fmaf(0.3275911f, ax, 1.0f));
  float p = __builtin_fmaf(1.061405429f, t, -1.453152027f);
  p = __builtin_fmaf(p, t, 1.421413741f);
  p = __builtin_fmaf(p, t, -0.284496736f);
  p = __builtin_fmaf(p, t, 0.254829592f);
  p = p*t;
  float e = __expf(-ax*ax);
  float y = __builtin_fmaf(-p, e, 1.0f);
  return __builtin_copysignf(y, x);
}
__device__ __forceinline__ float gelu_fe(float x){
  return 0.5f*x*(1.0f + erf_fast(x*0.7071067811865476f));
}

// ---------------- k_front: prep (blocks 0..511) ∪ fe_a (blocks 512..1023) ----------------
// fe_a GEMVs coalesced via wave-level k-striping: thread (o4=lt>>5, kl=lt&31)
// computes a k-strided partial for output oc*4+o4 — 32 lanes read 32 consecutive
// floats (one 128B segment) — then 5 shfl_xor (masks 1..16, within the 32-lane
// group) reduce. No LDS tiles, no staging barriers (R18's tile approach
// regressed: 16 barrier phases + VGPR 124). f32 reassociation only (R2-proven
// class on these exact chains).

__global__ __launch_bounds__(256) void k_front(
    const float* __restrict__ fe2W, const float* __restrict__ preW,
    const float* __restrict__ outW, const float* __restrict__ ffn1W,
    const float* __restrict__ ffn2W, const float* __restrict__ f1W,
    const float* __restrict__ f2W, const float* __restrict__ aemb,
    const int* __restrict__ nf, const float* __restrict__ bemb,
    const float* __restrict__ preb,
    ushortt* __restrict__ wbf, float* __restrict__ gs, float* __restrict__ xf0,
    float* __restrict__ outWT, float* __restrict__ ffn1WT, float* __restrict__ ffn2WT,
    float* __restrict__ f1WT, float* __restrict__ f2WT, float* __restrict__ bondWall,
    const float* __restrict__ e, const float* __restrict__ eigW,
    const float* __restrict__ eigb, const float* __restrict__ g,
    const float* __restrict__ bt, const float* __restrict__ qkvW,
    const float* __restrict__ qkvb,
    float* __restrict__ eigout, float* __restrict__ q,
    float* __restrict__ kT, float* __restrict__ v){
  int blk = blockIdx.x;
  int tid = threadIdx.x;
  if (blk < 512){
    int idx = blk*256 + tid;
    if (idx < 10240) gs[idx] = 0.f;            // 4 layers x 2560
    if (idx < 81920){
      float vv = (idx < 16384) ? fe2W[idx] : preW[idx - 16384];
      wbf[idx] = f2us(vv);
    }
    if (idx < 131072){
      int node = idx >> 7, h2 = idx & 127;
      xf0[idx] = aemb[nf[node]*HH + h2];
    }
    if (idx < 16384){ int o = idx>>7, m = idx&127;
      outWT[m*128+o]  = outW[idx];
      ffn1WT[m*128+o] = ffn1W[idx];
      ffn2WT[m*128+o] = ffn2W[idx];
    }
    if (idx < 65536){ int l = idx>>14, r = idx&16383; int o = r>>7, m = r&127;
      f1WT[l*16384 + m*128+o] = f1W[idx];
      f2WT[l*16384 + m*128+o] = f2W[idx];
    }
    if (idx < 5120){
      int l = idx / 1280; int r = idx - l*1280; int e2 = r >> 7; int hcol = r & 127;
      const float* br = bemb + e2*128;
      const float* wr = preW + l*16384 + hcol*128;
      float acc = preb[l*128 + hcol];
      for (int m=0;m<128;m++) acc += br[m]*wr[m];
      bondWall[idx] = acc;
    }
    return;
  }
  // ---- fe_a: 2 rows per block; coalesced k-striped GEMVs ----
  int sub = tid >> 7, lt = tid & 127;
  int row = (blk - 512)*2 + sub;
  int b = row >> 7, n = row & 127;
  int o4 = lt >> 5, kl = lt & 31;
  __shared__ float ee[2][129]; __shared__ float buf[2][128]; __shared__ float xm[2][128];
  __shared__ float xo[2][128];
  float ev = e[row];
  if (lt < 64){
    float dv = expf(-0.1439115683121279f * (float)lt);
    float pe = ev * 100.0f * dv;
    ee[sub][1+lt] = sinf(pe);
    ee[sub][65+lt] = cosf(pe);
  }
  if (lt == 0) ee[sub][0] = ev;
  __syncthreads();
  // eig GEMV: 32 passes x 4 outputs; k-strided partials + shfl tree-reduce
  for (int oc = 0; oc < 32; oc++){
    int o = oc*4 + o4;
    const float* wr = eigW + o*129;
    float p = ee[sub][kl]*wr[kl] + ee[sub][kl+32]*wr[kl+32]
            + ee[sub][kl+64]*wr[kl+64] + ee[sub][kl+96]*wr[kl+96];
    p += __shfl_xor(p, 1, 64);  p += __shfl_xor(p, 2, 64);
    p += __shfl_xor(p, 4, 64);  p += __shfl_xor(p, 8, 64);
    p += __shfl_xor(p, 16, 64);
    if (kl == 0) xo[sub][o] = p;
  }
  __syncthreads();
  float x = eigb[lt] + xo[sub][lt] + ee[sub][128]*eigW[lt*129+128];
  eigout[row*HH+lt] = x;
  buf[sub][lt]=x; __syncthreads();
  for (int s2=64;s2>0;s2>>=1){ if(lt<s2) buf[sub][lt]+=buf[sub][lt+s2]; __syncthreads(); }
  float mean = buf[sub][0]*(1.0f/128.0f); __syncthreads();
  float d = x-mean; buf[sub][lt]=d*d; __syncthreads();
  for (int s2=64;s2>0;s2>>=1){ if(lt<s2) buf[sub][lt]+=buf[sub][lt+s2]; __syncthreads(); }
  float var = buf[sub][0]*(1.0f/128.0f);
  xm[sub][lt] = d*rsqrtf(var+EPSV)*g[lt]+bt[lt];
  __syncthreads();
  #pragma unroll
  for (int s3=0;s3<3;s3++){
    for (int oc = 0; oc < 32; oc++){
      int o = oc*4 + o4;
      const float* wr = qkvW + (s3*HH+o)*128;
      float p = xm[sub][kl]*wr[kl] + xm[sub][kl+32]*wr[kl+32]
              + xm[sub][kl+64]*wr[kl+64] + xm[sub][kl+96]*wr[kl+96];
      p += __shfl_xor(p, 1, 64);  p += __shfl_xor(p, 2, 64);
      p += __shfl_xor(p, 4, 64);  p += __shfl_xor(p, 8, 64);
      p += __shfl_xor(p, 16, 64);
      if (kl == 0) xo[sub][o] = p;
    }
    __syncthreads();
    float acc = qkvb[s3*HH+lt] + xo[sub][lt];
    if (s3==0) q[row*HH+lt]=acc;
    else if (s3==1) kT[b*16384 + lt*128 + n]=acc;
    else v[row*HH+lt]=acc;
    __syncthreads();
  }
}

// fused attention + out-proj + LN + FFN + dec per (b,qi) — R10-proven.
__global__ __launch_bounds__(512) void k_attc(const float* __restrict__ q,
    const float* __restrict__ kT, const float* __restrict__ v,
    const float* __restrict__ eig, const int* __restrict__ length,
    const float* __restrict__ outWT, const float* __restrict__ outb,
    const float* __restrict__ fng, const float* __restrict__ fnb,
    const float* __restrict__ w1T, const float* __restrict__ b1,
    const float* __restrict__ w2T, const float* __restrict__ b2,
    const float* __restrict__ dW, const float* __restrict__ db,
    float* __restrict__ newe, float* __restrict__ outp){
  int row = blockIdx.x; int b = row>>7, qi = row&127;
  int tid = threadIdx.x;
  int hg = tid>>7, lt = tid&127;     // hg doubles as the m/j slice index
  int len = length[b];
  __shared__ float qv[4][DHD];
  __shared__ float red[4][128];
  __shared__ float satt[4][128];
  __shared__ float part[4][128];
  __shared__ float sc[128], sbuf[128], sxm[128], stt[128], sx[128];
  if (lt < DHD) qv[hg][lt] = q[(b*NN+qi)*HH + hg*DHD + lt];
  __syncthreads();
  float s = -1e30f;
  if (lt < len){
    const float* kr = kT + b*16384 + hg*DHD*128 + lt;
    float scr=0.f;
    for (int d2=0; d2<DHD; d2++) scr += qv[hg][d2]*kr[d2*128];
    s = scr * 0.17677669529663687f;
  }
  red[hg][lt]=s; __syncthreads();
  for (int st=64;st>0;st>>=1){ if(lt<st) red[hg][lt]=fmaxf(red[hg][lt],red[hg][lt+st]); __syncthreads(); }
  float mx = red[hg][0]; __syncthreads();
  float pp = (lt<len)? expf(s-mx):0.0f;
  red[hg][lt]=pp; __syncthreads();
  for (int st=64;st>0;st>>=1){ if(lt<st) red[hg][lt]+=red[hg][lt+st]; __syncthreads(); }
  float a = pp / red[hg][0];
  satt[hg][lt] = a;
  outp[4104 + ((b*NHD+hg)*NN+qi)*NN + lt] = a;
  __syncthreads();
  {
    int hd = lt>>5;
    float p=0.f;
    for (int j=hg*32; j<hg*32+32; j++) p += satt[hd][j]*v[(b*NN+j)*HH+lt];
    part[hg][lt]=p;
  }
  __syncthreads();
  if (tid < 128) sc[tid] = (part[0][tid]+part[1][tid])+(part[2][tid]+part[3][tid]);
  __syncthreads();
  {
    float p = (hg==0)? outb[lt] : 0.f;
    for (int m=hg*32; m<hg*32+32; m++) p += sc[m]*outWT[m*128+lt];
    part[hg][lt]=p;
  }
  __syncthreads();
  if (tid < 128){
    float x = eig[row*HH+tid] + ((part[0][tid]+part[1][tid])+(part[2][tid]+part[3][tid]));
    sx[tid] = x; sbuf[tid] = x;
  }
  __syncthreads();
  for (int s2=64;s2>0;s2>>=1){ if(tid<s2) sbuf[tid]+=sbuf[tid+s2]; __syncthreads(); }
  float mean = sbuf[0]*(1.f/128.f); __syncthreads();
  if (tid < 128){ float d = sx[tid]-mean; sbuf[tid]=d*d; }
  __syncthreads();
  for (int s2=64;s2>0;s2>>=1){ if(tid<s2) sbuf[tid]+=sbuf[tid+s2]; __syncthreads(); }
  float var = sbuf[0]*(1.f/128.f);
  if (tid < 128){
    float d = sx[tid]-mean;
    sxm[tid] = d*rsqrtf(var+EPSV)*fng[tid]+fnb[tid];
  }
  __syncthreads();
  {
    float p = (hg==0)? b1[lt] : 0.f;
    for (int m=hg*32; m<hg*32+32; m++) p += sxm[m]*w1T[m*128+lt];
    part[hg][lt]=p;
  }
  __syncthreads();
  if (tid < 128) stt[tid]=gelu_f((part[0][tid]+part[1][tid])+(part[2][tid]+part[3][tid]));
  __syncthreads();
  {
    float p = (hg==0)? b2[lt] : 0.f;
    for (int m=hg*32; m<hg*32+32; m++) p += stt[m]*w2T[m*128+lt];
    part[hg][lt]=p;
  }
  __syncthreads();
  if (tid < 128) sx[tid] = sx[tid] + ((part[0][tid]+part[1][tid])+(part[2][tid]+part[3][tid]));
  __syncthreads();
  if (tid < 4){
    float acc = db[tid];
    const float* wr = dW + tid*HH;
    for (int h2=0;h2<HH;h2++) acc += sx[h2]*wr[h2];
    int idx=(b*NHD+tid)*NN+qi;
    newe[idx]=acc; outp[8+idx]=acc;
  }
}

// ---------------- k_bx: xwl2-0 (blocks 0..15) ∪ fe2 (blocks 16..1039) — R14-proven ----
__global__ __launch_bounds__(512) void k_bx(const float* __restrict__ u,
    const float* __restrict__ newe,
    const float* __restrict__ w1g, const float* __restrict__ b1g,
    const ushortt* __restrict__ w2bf, const float* __restrict__ b2g,
    const int* __restrict__ length,
    bf16* __restrict__ bases,
    const float* __restrict__ xf0, const ushortt* __restrict__ wbfl0,
    float* __restrict__ xfW){
  int blk = blockIdx.x;
  int tid = threadIdx.x;
  __shared__ alignas(16) char us[38400];
  if (blk < 16){
    // ---- xwl2 layer 0: two 256-thread halves, each one (b,rq) item ----
    int sub = tid >> 8, lt = tid & 255;
    int item = blk*2 + sub;
    int b = item >> 2, rq = item & 3;
    int lane = lt & 63, w = lt >> 6, quad = lane >> 4, l15 = lane & 15;
    ushortt* sA = (ushortt*)(us + sub*8704);    // [32][136] per half
    for (int idx = lt; idx < 1024; idx += 256){
      int r = idx >> 5, c = idx & 31;
      int gr = b*128 + rq*32 + r;
      float4 xv = ((const float4*)xf0)[gr*32 + c];
      ushort4 o;
      o.x=f2us(xv.x); o.y=f2us(xv.y); o.z=f2us(xv.z); o.w=f2us(xv.w);
      *(ushort4*)&sA[r*136 + c*4] = o;
    }
    __syncthreads();
    f32x4 acc[2][2];
    #pragma unroll
    for (int mt=0;mt<2;mt++)
      #pragma unroll
      for (int nt=0;nt<2;nt++) acc[mt][nt] = (f32x4){0.f,0.f,0.f,0.f};
    #pragma unroll
    for (int kk = 0; kk < 128; kk += 32){
      bf16x8 af[2], bfr[2];
      #pragma unroll
      for (int mt=0;mt<2;mt++) af[mt] = *(const bf16x8*)&sA[(mt*16+l15)*136 + kk + quad*8];
      #pragma unroll
      for (int nt=0;nt<2;nt++) bfr[nt] = *(const bf16x8*)&wbfl0[((w*2+nt)*16+l15)*128 + kk + quad*8];
      #pragma unroll
      for (int mt=0;mt<2;mt++)
        #pragma unroll
        for (int nt=0;nt<2;nt++)
          acc[mt][nt] = __builtin_amdgcn_mfma_f32_16x16x32_bf16(af[mt], bfr[nt], acc[mt][nt], 0, 0, 0);
    }
    #pragma unroll
    for (int mt=0;mt<2;mt++)
      #pragma unroll
      for (int nt=0;nt<2;nt++){
        int h = (w*2+nt)*16 + l15;
        #pragma unroll
        for (int reg=0;reg<4;reg++){
          int prr = rq*32 + mt*16 + quad*4 + reg;
          xfW[(b*128 + prr)*128 + h] = acc[mt][nt][reg];
        }
      }
    return;
  }
  // ---- fe2: one block per bi, 8 waves cover all 128 A-rows ----
  int bi = blk - 16;
  int b = bi >> 7;
  int nloc = bi & 127;
  int len = length[b];
  if (nloc >= len) return;
  int lane = tid & 63, w = tid >> 6, quad = lane >> 4, l15 = lane & 15;
  int pr = w*16 + l15;
  ushortt* sW2 = (ushortt*)us;                  // 32768B; reused as sT (two passes)
  float* w1a = (float*)(us + 32768);            // 2048B
  float* w1b = (float*)(us + 34816);            // 1024B
  float* b2s = (float*)(us + 35840);            // 512B
  float* cn  = (float*)(us + 36352);            // [4][128] = 2048B
  for (int idx = tid; idx < 2048; idx += 512){
    int r = idx >> 4, cb = idx & 15;
    *(uint4*)&sW2[r*128 + ((cb*8) ^ ((r&15)<<3))] = *(const uint4*)&w2bf[r*128 + cb*8];
  }
  if (tid < 128){
    w1a[tid*4+0] = b1g[tid];
    w1a[tid*4+1] = w1g[tid*5+0];
    w1a[tid*4+2] = w1g[tid*5+1];
    w1a[tid*4+3] = w1g[tid*5+2];
    w1b[tid*2+0] = w1g[tid*5+3];
    w1b[tid*2+1] = w1g[tid*5+4];
    b2s[tid] = b2g[tid];
  }
  if (tid < 512){
    int k = tid >> 7, m = tid & 127;
    cn[k*128+m] = u[(b*NN+nloc)*NN + m] * newe[(b*NHD+k)*NN + m];
  }
  __syncthreads();
  bool wact = (w*16) < len;     // rows >= len in active waves are computed but never stored
  f32x4 acc[8];
  #pragma unroll
  for (int nt=0;nt<8;nt++) acc[nt] = (f32x4){0.f,0.f,0.f,0.f};
  if (wact){
    float f0=0.f, f1=0.f, f2v=0.f, f3=0.f;
    const float4* ur = (const float4*)(u + ((size_t)b*NN + pr)*NN);
    for (int m4 = quad*8; m4 < quad*8+8; m4++){
      float4 uv = ur[m4];
      int m = m4*4;
      f0 += cn[m]*uv.x; f0 += cn[m+1]*uv.y; f0 += cn[m+2]*uv.z; f0 += cn[m+3]*uv.w;
      f1 += cn[128+m]*uv.x; f1 += cn[128+m+1]*uv.y; f1 += cn[128+m+2]*uv.z; f1 += cn[128+m+3]*uv.w;
      f2v += cn[256+m]*uv.x; f2v += cn[256+m+1]*uv.y; f2v += cn[256+m+2]*uv.z; f2v += cn[256+m+3]*uv.w;
      f3 += cn[384+m]*uv.x; f3 += cn[384+m+1]*uv.y; f3 += cn[384+m+2]*uv.z; f3 += cn[384+m+3]*uv.w;
    }
    f0 += __shfl_xor(f0, 16, 64);  f0 += __shfl_xor(f0, 32, 64);
    f1 += __shfl_xor(f1, 16, 64);  f1 += __shfl_xor(f1, 32, 64);
    f2v += __shfl_xor(f2v, 16, 64); f2v += __shfl_xor(f2v, 32, 64);
    f3 += __shfl_xor(f3, 16, 64);  f3 += __shfl_xor(f3, 32, 64);
    float dg = (pr == nloc) ? 1.0f : 0.0f;
    for (int kk = 0; kk < 128; kk += 32){
      bf16x8 af;
      #pragma unroll
      for (int j=0;j<8;j++){
        int m = kk + quad*8 + j;
        const float4 wa = *(const float4*)&w1a[m*4];
        const float2 wb = *(const float2*)&w1b[m*2];
        float a = wa.x + wa.y*dg + wa.z*f0 + wa.w*f1 + wb.x*f2v + wb.y*f3;
        af[j] = (short)f2us(gelu_fe(a));
      }
      #pragma unroll
      for (int nt=0;nt<8;nt++){
        int rowb = nt*16 + l15;
        int off = (kk + quad*8) ^ (l15 << 3);   // ushort units; rowb&15 == l15
        bf16x8 bfr = *(const bf16x8*)&sW2[rowb*128 + off];
        acc[nt] = __builtin_amdgcn_mfma_f32_16x16x32_bf16(af, bfr, acc[nt], 0, 0, 0);
      }
    }
  }
  __syncthreads();              // all sW2 MFMA reads done -> reuse as sT
  ushortt* sT = sW2;            // [64][132] per pass
  // pass 1: rows 0..63 (waves 0..3)
  if (wact && w < 4){
    #pragma unroll
    for (int nt=0;nt<8;nt++){
      int h = nt*16 + l15;
      float bb = b2s[h];
      #pragma unroll
      for (int reg=0;reg<4;reg++){
        int lr = w*16 + quad*4 + reg;
        sT[lr*132 + h] = f2us(gelu_fe(acc[nt][reg] + bb));
      }
    }
  }
  __syncthreads();
  {
    int rmax = len < 64 ? len : 64;
    ushort4* gout = (ushort4*)(bases + (size_t)bi*16384);
    for (int idx = tid; idx < rmax*32; idx += 512){
      int row = idx >> 5, seg = idx & 31;
      gout[idx] = *(const ushort4*)&sT[row*132 + seg*4];
    }
  }
  __syncthreads();
  // pass 2: rows 64..127 (waves 4..7)
  if (wact && w >= 4){
    #pragma unroll
    for (int nt=0;nt<8;nt++){
      int h = nt*16 + l15;
      float bb = b2s[h];
      #pragma unroll
      for (int reg=0;reg<4;reg++){
        int lr = (w-4)*16 + quad*4 + reg;
        sT[lr*132 + h] = f2us(gelu_fe(acc[nt][reg] + bb));
      }
    }
  }
  __syncthreads();
  {
    int rmax2 = len - 64; if (rmax2 < 0) rmax2 = 0; if (rmax2 > 64) rmax2 = 64;
    if (rmax2 > 0){
      ushort4* gout = (ushort4*)(bases + (size_t)bi*16384 + 64*128);
      for (int idx = tid; idx < rmax2*32; idx += 512){
        int row = idx >> 5, seg = idx & 31;
        gout[idx] = *(const ushort4*)&sT[row*132 + seg*4];
      }
    }
  }
}

// ---------------- message passing ----------------
// gs layout per layer (stride 2560): [bank0..7][sum1(128)|sq1(128)] + 2048:[sum2|sq2]

// xwl2: 64 blocks, 16 rows each; dead slabs return early (R16-proven).
__global__ __launch_bounds__(256) void k_xwl2(const float* __restrict__ xfprev,
    const float* __restrict__ t2, const float* __restrict__ gsum2p,
    const float* __restrict__ gsq2p, const float* __restrict__ g2p,
    const float* __restrict__ bb2p, const int* __restrict__ length,
    const ushortt* __restrict__ wbfl, float* __restrict__ xfB,
    float* __restrict__ xfW){
  int blk = blockIdx.x;
  int b = blk >> 3, r16 = blk & 7;
  if (r16*16 >= length[b]) return;   // dead 16-row slab: outputs never read
  int tid = threadIdx.x;
  int lane = tid & 63, w = tid >> 6, quad = lane >> 4, l15 = lane & 15;
  __shared__ alignas(16) ushortt sA[16*136];
  __shared__ float smu[128], sistd[128], sg[128], sbb[128];
  if (tid < 128){
    float cnt = 0.f;
    for (int q2=0;q2<BB;q2++) cnt += (float)length[q2];
    float mu = gsum2p[tid]/cnt;
    float var = gsq2p[tid]/cnt - mu*mu;
    smu[tid]=mu; sistd[tid]=rsqrtf(fmaxf(var,0.0f)+EPSV);
    sg[tid]=g2p[tid]; sbb[tid]=bb2p[tid];
  }
  __syncthreads();
  for (int idx = tid; idx < 512; idx += 256){
    int r = idx >> 5, c = idx & 31;
    int gr = b*128 + r16*16 + r;
    float4 xv = ((const float4*)xfprev)[gr*32 + c];
    float4 tv = ((const float4*)t2)[gr*32 + c];
    int f0 = c*4;
    xv.x += fmaxf((tv.x-smu[f0+0])*sistd[f0+0]*sg[f0+0]+sbb[f0+0], 0.f);
    xv.y += fmaxf((tv.y-smu[f0+1])*sistd[f0+1]*sg[f0+1]+sbb[f0+1], 0.f);
    xv.z += fmaxf((tv.z-smu[f0+2])*sistd[f0+2]*sg[f0+2]+sbb[f0+2], 0.f);
    xv.w += fmaxf((tv.w-smu[f0+3])*sistd[f0+3]*sg[f0+3]+sbb[f0+3], 0.f);
    ((float4*)xfB)[gr*32 + c] = xv;
    ushort4 o;
    o.x=f2us(xv.x); o.y=f2us(xv.y); o.z=f2us(xv.z); o.w=f2us(xv.w);
    *(ushort4*)&sA[r*136 + c*4] = o;
  }
  __syncthreads();
  f32x4 acc[2];
  #pragma unroll
  for (int nt=0;nt<2;nt++) acc[nt] = (f32x4){0.f,0.f,0.f,0.f};
  #pragma unroll
  for (int kk = 0; kk < 128; kk += 32){
    bf16x8 af = *(const bf16x8*)&sA[l15*136 + kk + quad*8];
    #pragma unroll
    for (int nt=0;nt<2;nt++){
      bf16x8 bfr = *(const bf16x8*)&wbfl[((w*2+nt)*16+l15)*128 + kk + quad*8];
      acc[nt] = __builtin_amdgcn_mfma_f32_16x16x32_bf16(af, bfr, acc[nt], 0, 0, 0);
    }
  }
  #pragma unroll
  for (int nt=0;nt<2;nt++){
    int h = (w*2+nt)*16 + l15;
    #pragma unroll
    for (int reg=0;reg<4;reg++){
      int prr = r16*16 + quad*4 + reg;
      xfW[(b*128 + prr)*128 + h] = acc[nt][reg];
    }
  }
}

// per-edge elementwise + FUSED g1 GEMM + BN1 partial stats (R16-proven, len-masked)
__global__ __launch_bounds__(512) void k_edge(const float* __restrict__ xfin, float* __restrict__ xfout,
    const bf16* __restrict__ bases, const float* __restrict__ xfW,
    const float* __restrict__ bondWl, const int* __restrict__ ef,
    const int* __restrict__ length,
    const float* __restrict__ w1t, const float* __restrict__ bias1,
    float* __restrict__ t1, float* __restrict__ gst){
  int bj = blockIdx.x; int b = bj >> 7, j = bj & 127;
  int len = length[b];
  if (j >= len) return;               // dead row: outputs never read
  int tid = threadIdx.x;
  int is = tid >> 6, hp = tid & 63;   // i-slice 0..7, h-pair 0..63
  int h2 = hp*2;
  __shared__ float sBW[10][128];
  __shared__ int sEf[128];
  __shared__ float part[8][128];
  for (int idx = tid; idx < 1280; idx += 512) sBW[idx>>7][idx&127] = bondWl[idx];
  if (tid < 128) sEf[tid] = ef[(b*NN + tid)*NN + j];
  __syncthreads();
  float a0 = 0.f, a1 = 0.f;
  {
    const float* xwb = xfW + b*NN*HH;
    const ushortt* bb = (const ushortt*)(bases + ((size_t)b*NN + j)*NN*HH);
    for (int i = is; i < len; i += 8){
      int ev = sEf[i];
      float2 xw = *(const float2*)&xwb[i*128 + h2];
      float2 bw = *(const float2*)&sBW[ev][h2];
      unsigned bv = *(const unsigned*)&bb[i*128 + h2];
      float v0 = gelu_h(xw.x + bw.x);
      float v1 = gelu_h(xw.y + bw.y);
      a0 += v0 * us2f((ushortt)(bv & 0xffffu));
      a1 += v1 * us2f((ushortt)(bv >> 16));
    }
  }
  part[is][h2] = a0; part[is][h2+1] = a1;
  __syncthreads();
  if (tid < 128){
    int o = (b*NN + j)*HH + tid;
    float xrow = xfin[o]
      + ((part[0][tid]+part[1][tid])+(part[2][tid]+part[3][tid]))
      + ((part[4][tid]+part[5][tid])+(part[6][tid]+part[7][tid]));
    xfout[o] = xrow;
    part[0][tid] = xrow;      // own-column read->write, no race
  }
  __syncthreads();
  // g1 GEMM on the row + BN1 partial stats
  int h = tid & 127, ih = tid >> 7;
  float acc = (ih==0) ? bias1[h] : 0.f;
  {
    const float* wcol = w1t + h;
    int m0 = ih*32;
    for (int m = m0; m < m0+32; m++) acc += part[0][m]*wcol[m*128];
  }
  float* red = &sBW[0][0];
  __syncthreads();
  red[ih*128 + h] = acc; __syncthreads();
  if (tid < 128){
    float t1v = red[tid] + red[128+tid] + red[256+tid] + red[384+tid];
    t1[(b*NN + j)*HH + tid] = t1v;
    int bank = bj & 7;
    atomicAdd(&gst[bank*256 + tid], t1v);
    atomicAdd(&gst[bank*256 + 128 + tid], t1v*t1v);
  }
}

// finalize BN1 (sum 8 banks) + relu + g2 GEMM + partial BN2 stats (R17-proven)
__global__ __launch_bounds__(512) void k_g2s(const float* __restrict__ t1,
    const float* __restrict__ gstL,
    const float* __restrict__ g1, const float* __restrict__ bb1,
    const float* __restrict__ w2t, const float* __restrict__ bias2,
    const int* __restrict__ length, float* __restrict__ t2){
  int blk = blockIdx.x; int tid = threadIdx.x;
  int r0 = blk*4;
  {
    int b0 = r0 >> 7, n0 = r0 & 127;
    if (n0 >= length[b0]) return;    // whole 4-row group dead (groups never cross b)
  }
  int f = tid & 127, rh = tid >> 7;   // rh 0..3
  __shared__ float sy[4][128];
  __shared__ float red1[4][128], red2[4][128];
  float cnt = 0.f;
  for (int b=0;b<BB;b++) cnt += (float)length[b];
  float su = 0.f, sq = 0.f;
  #pragma unroll
  for (int k=0;k<8;k++){ su += gstL[k*256 + f]; sq += gstL[k*256 + 128 + f]; }
  float mu = su/cnt;
  float var = sq/cnt - mu*mu;
  float istd = rsqrtf(fmaxf(var,0.0f)+EPSV);
  float gg = g1[f], bbv = bb1[f];
  int rg = r0 + rh; int b = rg >> 7, n = rg & 127;
  bool live = (n < length[b]);
  if (live){
    float x = t1[rg*128 + f];
    float y = (x-mu)*istd*gg + bbv;
    sy[rh][f] = fmaxf(y, 0.0f);
  }
  __syncthreads();
  float s = 0.f, s2 = 0.f;
  if (live){
    float acc = bias2[f];
    for (int m=0;m<128;m++) acc += sy[rh][m]*w2t[m*128+f];
    t2[rg*128+f] = acc;
    s = acc; s2 = acc*acc;
  }
  red1[rh][f]=s; red2[rh][f]=s2; __syncthreads();
  if (tid < 128){
    atomicAdd((float*)&gstL[2048 + tid], (red1[0][tid]+red1[1][tid])+(red1[2][tid]+red1[3][tid]));
    atomicAdd((float*)&gstL[2048 + 128 + tid], (red2[0][tid]+red2[1][tid])+(red2[2][tid]+red2[3][tid]));
  }
}

// final BN2-apply fused into pooling + linear head (R17-proven, 512 thr)
__global__ __launch_bounds__(512) void k_pool2(const float* __restrict__ xf, const float* __restrict__ t2,
                        const float* __restrict__ gsum2, const float* __restrict__ gsq2,
                        const float* __restrict__ g2, const float* __restrict__ bb2,
                        const int* __restrict__ length,
                        const float* lw, const float* lb, float* __restrict__ outp){
  int b = blockIdx.x, tid=threadIdx.x;
  int h = tid & 127, slice = tid >> 7;
  int len = length[b];
  float cnt = 0.f;
  for (int q2=0;q2<BB;q2++) cnt += (float)length[q2];
  float mu = gsum2[h]/cnt;
  float var = gsq2[h]/cnt - mu*mu;
  float istd = rsqrtf(fmaxf(var,0.0f)+EPSV);
  float gg = g2[h], bbv = bb2[h];
  float s=0.f;
  for (int n2=slice; n2<len; n2+=4){
    int o = (b*NN+n2)*HH+h;
    float x = xf[o] + fmaxf((t2[o]-mu)*istd*gg+bbv, 0.0f);
    s += x;
  }
  __shared__ float part[4][128];
  __shared__ float red[128];
  part[slice][h] = s; __syncthreads();
  if (tid < 128){
    float ss = (part[0][tid]+part[1][tid])+(part[2][tid]+part[3][tid]);
    ss /= (float)len;
    red[tid] = ss*lw[tid];
  }
  __syncthreads();
  for (int st=64;st>0;st>>=1){ if(tid<st) red[tid]+=red[tid+st]; __syncthreads(); }
  if (tid==0) outp[b]=red[0]+lb[0];
}

// ---------------- host ----------------

extern "C" void kernel_launch(void* const* d_in, const int* in_sizes, int n_in,
                              void* d_out, int out_size, void* d_ws, size_t ws_size,
                              hipStream_t stream) {
  (void)in_sizes; (void)n_in; (void)out_size; (void)ws_size;
  const float* e        = (const float*)d_in[0];
  const float* u        = (const float*)d_in[1];
  const float* atom_emb = (const float*)d_in[2];
  const float* bond_emb = (const float*)d_in[3];
  const float* eigw_W   = (const float*)d_in[4];
  const float* eigw_b   = (const float*)d_in[5];
  const float* mng      = (const float*)d_in[6];
  const float* mnb      = (const float*)d_in[7];
  const float* qkvW     = (const float*)d_in[8];
  const float* qkvb     = (const float*)d_in[9];
  const float* outW     = (const float*)d_in[10];
  const float* outb     = (const float*)d_in[11];
  const float* fng      = (const float*)d_in[12];
  const float* fnb      = (const float*)d_in[13];
  const float* ffn1W    = (const float*)d_in[14];
  const float* ffn1b    = (const float*)d_in[15];
  const float* ffn2W    = (const float*)d_in[16];
  const float* ffn2b    = (const float*)d_in[17];
  const float* decW     = (const float*)d_in[18];
  const float* decb     = (const float*)d_in[19];
  const float* fe1W     = (const float*)d_in[20];
  const float* fe1b     = (const float*)d_in[21];
  const float* fe2W     = (const float*)d_in[22];
  const float* fe2b     = (const float*)d_in[23];
  const float* preW     = (const float*)d_in[24];
  const float* preb     = (const float*)d_in[25];
  const float* f1W      = (const float*)d_in[26];
  const float* f1b      = (const float*)d_in[27];
  const float* bn1g     = (const float*)d_in[28];
  const float* bn1b     = (const float*)d_in[29];
  const float* f2W      = (const float*)d_in[30];
  const float* f2b      = (const float*)d_in[31];
  const float* bn2g     = (const float*)d_in[32];
  const float* bn2b     = (const float*)d_in[33];
  const float* linW     = (const float*)d_in[34];
  const float* linb     = (const float*)d_in[35];
  const int* nodef      = (const int*)d_in[36];
  const int* edgef      = (const int*)d_in[37];
  const int* length     = (const int*)d_in[38];

  float* outp = (float*)d_out;   // h[8] ++ new_e[4096] ++ attn[524288], f32

  char* p = (char*)d_ws;
  auto alloc = [&](size_t bytes)->void*{ void* r=(void*)p; p += (bytes+255)&~(size_t)255; return r; };
  const int TOK = BB*NN*HH;           // 131072
  float* eig   = (float*)alloc(TOK*4);
  float* q     = (float*)alloc(TOK*4);
  float* kT    = (float*)alloc(TOK*4);
  float* v     = (float*)alloc(TOK*4);
  float* newe  = (float*)alloc(BB*NHD*NN*4);
  bf16*  bases = (bf16*) alloc((size_t)BB*NN*NN*HH*2);
  float* xf0   = (float*)alloc(TOK*4);
  float* xfB   = (float*)alloc(TOK*4);
  float* xfC   = (float*)alloc(TOK*4);
  float* xfD   = (float*)alloc(TOK*4);
  float* t1    = (float*)alloc(TOK*4);
  float* t2    = (float*)alloc(TOK*4);
  float* xfW   = (float*)alloc(TOK*4);
  float* gs    = (float*)alloc(10240*4);         // 4 layers x 2560
  ushortt* wbf = (ushortt*)alloc(81920*2);
  float* outWT = (float*)alloc(16384*4);
  float* ffn1WT= (float*)alloc(16384*4);
  float* ffn2WT= (float*)alloc(16384*4);
  float* f1WT  = (float*)alloc(65536*4);
  float* f2WT  = (float*)alloc(65536*4);
  float* bondWall = (float*)alloc(5120*4);

  // front: prep (blocks 0..511) + fe_a (blocks 512..1023, 2 rows/block)
  k_front<<<1024, 256, 0, stream>>>(fe2W, preW, outW, ffn1W, ffn2W,
                                    f1W, f2W, atom_emb, nodef, bond_emb, preb,
                                    wbf, gs, xf0, outWT, ffn1WT, ffn2WT,
                                    f1WT, f2WT, bondWall,
                                    e, eigw_W, eigw_b, mng, mnb, qkvW, qkvb,
                                    eig, q, kT, v);

  k_attc<<<BB*NN, 512, 0, stream>>>(q, kT, v, eig, length,
                                    outWT, outb, fng, fnb,
                                    ffn1WT, ffn1b, ffn2WT, ffn2b,
                                    decW, decb, newe, outp);

  // xwl2-0 (blocks 0..15) + bases fe2 (blocks 16..1039, one per bi)
  k_bx<<<16 + BB*NN, 512, 0, stream>>>(u, newe, fe1W, fe1b, wbf, fe2b, length,
                                       bases, xf0, wbf + 16384, xfW);

  // message passing
  const float* xfprev = xf0;
  float* xfcur = xfC;
  for (int l=0;l<LAY;l++){
    const ushortt* wbfl = wbf + 16384 + l*16384;
    float* gsl = gs + l*2560;
    float* gsp = gs + (l-1)*2560;
    if (l > 0){
      k_xwl2<<<BB*8, 256, 0, stream>>>(xfprev, t2, gsp+2048, gsp+2048+128,
                                       bn2g + (l-1)*HH, bn2b + (l-1)*HH,
                                       length, wbfl, xfB, xfW);
    }
    const float* xin = (l==0)? xf0 : xfB;
    k_edge<<<BB*NN, 512, 0, stream>>>(xin, xfcur, bases, xfW, bondWall + l*1280,
                                      edgef, length,
                                      f1WT + l*16384, f1b + l*HH, t1, gsl);
    k_g2s<<<256, 512, 0, stream>>>(t1, gsl, bn1g + l*HH, bn1b + l*HH,
                                   f2WT + l*16384, f2b + l*HH, length, t2);
    xfprev = xfcur;
    xfcur = (xfcur == xfC) ? xfD : xfC;
  }
  // final: BN2(layer3) applied inside pool (xfprev holds layer-3 output)
  k_pool2<<<BB, 512, 0, stream>>>(xfprev, t2, gs+3*2560+2048, gs+3*2560+2048+128,
                                  bn2g + 3*HH, bn2b + 3*HH, length, linW, linb, outp);
}

// Round 20
// 338.830 us; speedup vs baseline: 1.0922x; 1.0922x over previous
//
#include <hip/hip_runtime.h>
#include <hip/hip_bf16.h>
#include <math.h>

#define BB 8
#define NN 128
#define HH 128
#define NHD 4
#define DHD 32
#define LAY 4
#define EPSV 1e-5f

typedef __hip_bfloat16 bf16;
typedef unsigned short ushortt;
typedef short bf16x8 __attribute__((ext_vector_type(8)));
typedef float f32x4 __attribute__((ext_vector_type(4)));

__device__ __forceinline__ float b2f(bf16 x){ return __bfloat162float(x); }
__device__ __forceinline__ bf16 f2b(float x){ return __float2bfloat16(x); }
__device__ __forceinline__ float us2f(ushortt u){ return __uint_as_float(((unsigned)u)<<16); }
__device__ __forceinline__ ushortt f2us(float x){ bf16 b=__float2bfloat16(x); return *(ushortt*)&b; }
__device__ __forceinline__ float gelu_f(float x){ return 0.5f*x*(1.0f+erff(x*0.7071067811865476f)); }
// fast tanh-gelu — h-path serial loops only (k_edge); measured win there
__device__ __forceinline__ float gelu_h(float x){
  float t = 0.7978845608028654f*x*(1.0f + 0.044715f*x*x);
  float e = __expf(2.0f*t);
  float th = 1.0f - 2.0f/(e + 1.0f);
  return 0.5f*x*(1.0f + th);
}
// branch-free A&S 7.1.26 erf (|err| <= 1.5e-7)
__device__ __forceinline__ float erf_fast(float x){
  float ax = fabsf(x);
  float t = __builtin_amdgcn_rcpf(__builtin_fmaf(0.3275911f, ax, 1.0f));
  float p = __builtin_fmaf(1.061405429f, t, -1.453152027f);
  p = __builtin_fmaf(p, t, 1.421413741f);
  p = __builtin_fmaf(p, t, -0.284496736f);
  p = __builtin_fmaf(p, t, 0.254829592f);
  p = p*t;
  float e = __expf(-ax*ax);
  float y = __builtin_fmaf(-p, e, 1.0f);
  return __builtin_copysignf(y, x);
}
__device__ __forceinline__ float gelu_fe(float x){
  return 0.5f*x*(1.0f + erf_fast(x*0.7071067811865476f));
}

// ---------------- prep (R10 form: transposes restored so fe_a reads coalesced) ----------------
// R11's prep∪fe_a merge forced fe_a onto original weight layouts (516B inter-lane
// stride, uncoalesced) — cost ~25us vs the ~4us dispatch it saved. Un-merged.

__global__ __launch_bounds__(256) void k_prep(const float* __restrict__ fe2W,
    const float* __restrict__ preW, const float* __restrict__ eigW,
    const float* __restrict__ qkvW, const float* __restrict__ outW,
    const float* __restrict__ ffn1W, const float* __restrict__ ffn2W,
    const float* __restrict__ f1W, const float* __restrict__ f2W,
    const float* __restrict__ aemb, const int* __restrict__ nf,
    const float* __restrict__ bemb, const float* __restrict__ preb,
    ushortt* __restrict__ wbf, float* __restrict__ gs, float* __restrict__ xf0,
    float* __restrict__ eigWT, float* __restrict__ qkvWT, float* __restrict__ outWT,
    float* __restrict__ ffn1WT, float* __restrict__ ffn2WT,
    float* __restrict__ f1WT, float* __restrict__ f2WT,
    float* __restrict__ bondWall){
  int idx = blockIdx.x*256 + threadIdx.x;    // grid covers 131072
  if (idx < 10240) gs[idx] = 0.f;            // 4 layers x 2560
  if (idx < 81920){
    float v = (idx < 16384) ? fe2W[idx] : preW[idx - 16384];
    wbf[idx] = f2us(v);
  }
  if (idx < 131072){
    int node = idx >> 7, h2 = idx & 127;
    xf0[idx] = aemb[nf[node]*HH + h2];
  }
  if (idx < 16512){ int o = idx/129, kq = idx - o*129; eigWT[kq*128+o] = eigW[idx]; }
  if (idx < 49152){ int o = idx>>7, m = idx&127; qkvWT[m*384+o] = qkvW[idx]; }
  if (idx < 16384){ int o = idx>>7, m = idx&127;
    outWT[m*128+o]  = outW[idx];
    ffn1WT[m*128+o] = ffn1W[idx];
    ffn2WT[m*128+o] = ffn2W[idx];
  }
  if (idx < 65536){ int l = idx>>14, r = idx&16383; int o = r>>7, m = r&127;
    f1WT[l*16384 + m*128+o] = f1W[idx];
    f2WT[l*16384 + m*128+o] = f2W[idx];
  }
  if (idx < 5120){
    int l = idx / 1280; int r = idx - l*1280; int e2 = r >> 7; int hcol = r & 127;
    const float* br = bemb + e2*128;
    const float* wr = preW + l*16384 + hcol*128;
    float acc = preb[l*128 + hcol];
    for (int m=0;m<128;m++) acc += br[m]*wr[m];
    bondWall[idx] = acc;
  }
}

// ---------------- fe_a (exact R10 body: coalesced transposed reads) ----------------

__global__ void k_fe_a(const float* __restrict__ e, const float* __restrict__ eigWT,
                       const float* __restrict__ eigb, const float* __restrict__ g,
                       const float* __restrict__ bt, const float* __restrict__ qkvWT,
                       const float* __restrict__ qkvb,
                       float* __restrict__ eigout, float* __restrict__ q,
                       float* __restrict__ kT, float* __restrict__ v){
  int row = blockIdx.x; int tid = threadIdx.x;
  int b = row >> 7, n = row & 127;
  __shared__ float ee[129]; __shared__ float buf[128]; __shared__ float xm[128];
  float ev = e[row];
  if (tid < 64){
    float dv = expf(-0.1439115683121279f * (float)tid);
    float pe = ev * 100.0f * dv;
    ee[1+tid] = sinf(pe);
    ee[65+tid] = cosf(pe);
  }
  if (tid == 0) ee[0] = ev;
  __syncthreads();
  float x = eigb[tid];
  for (int k2=0;k2<129;k2++) x += ee[k2]*eigWT[k2*128+tid];
  eigout[row*HH+tid] = x;
  buf[tid]=x; __syncthreads();
  for (int s2=64;s2>0;s2>>=1){ if(tid<s2) buf[tid]+=buf[tid+s2]; __syncthreads(); }
  float mean = buf[0]*(1.0f/128.0f); __syncthreads();
  float d = x-mean; buf[tid]=d*d; __syncthreads();
  for (int s2=64;s2>0;s2>>=1){ if(tid<s2) buf[tid]+=buf[tid+s2]; __syncthreads(); }
  float var = buf[0]*(1.0f/128.0f);
  xm[tid] = d*rsqrtf(var+EPSV)*g[tid]+bt[tid];
  __syncthreads();
  #pragma unroll
  for (int s3=0;s3<3;s3++){
    float acc = qkvb[s3*HH+tid];
    const float* wt = qkvWT + s3*HH + tid;
    for (int m=0;m<HH;m++) acc += xm[m]*wt[m*384];
    if (s3==0) q[row*HH+tid]=acc;
    else if (s3==1) kT[b*16384 + tid*128 + n]=acc;
    else v[row*HH+tid]=acc;
  }
}

// fused attention + out-proj + LN + FFN + dec per (b,qi) — R10-proven.
__global__ __launch_bounds__(512) void k_attc(const float* __restrict__ q,
    const float* __restrict__ kT, const float* __restrict__ v,
    const float* __restrict__ eig, const int* __restrict__ length,
    const float* __restrict__ outWT, const float* __restrict__ outb,
    const float* __restrict__ fng, const float* __restrict__ fnb,
    const float* __restrict__ w1T, const float* __restrict__ b1,
    const float* __restrict__ w2T, const float* __restrict__ b2,
    const float* __restrict__ dW, const float* __restrict__ db,
    float* __restrict__ newe, float* __restrict__ outp){
  int row = blockIdx.x; int b = row>>7, qi = row&127;
  int tid = threadIdx.x;
  int hg = tid>>7, lt = tid&127;     // hg doubles as the m/j slice index
  int len = length[b];
  __shared__ float qv[4][DHD];
  __shared__ float red[4][128];
  __shared__ float satt[4][128];
  __shared__ float part[4][128];
  __shared__ float sc[128], sbuf[128], sxm[128], stt[128], sx[128];
  if (lt < DHD) qv[hg][lt] = q[(b*NN+qi)*HH + hg*DHD + lt];
  __syncthreads();
  float s = -1e30f;
  if (lt < len){
    const float* kr = kT + b*16384 + hg*DHD*128 + lt;
    float scr=0.f;
    for (int d2=0; d2<DHD; d2++) scr += qv[hg][d2]*kr[d2*128];
    s = scr * 0.17677669529663687f;
  }
  red[hg][lt]=s; __syncthreads();
  for (int st=64;st>0;st>>=1){ if(lt<st) red[hg][lt]=fmaxf(red[hg][lt],red[hg][lt+st]); __syncthreads(); }
  float mx = red[hg][0]; __syncthreads();
  float pp = (lt<len)? expf(s-mx):0.0f;
  red[hg][lt]=pp; __syncthreads();
  for (int st=64;st>0;st>>=1){ if(lt<st) red[hg][lt]+=red[hg][lt+st]; __syncthreads(); }
  float a = pp / red[hg][0];
  satt[hg][lt] = a;
  outp[4104 + ((b*NHD+hg)*NN+qi)*NN + lt] = a;
  __syncthreads();
  {
    int hd = lt>>5;
    float p=0.f;
    for (int j=hg*32; j<hg*32+32; j++) p += satt[hd][j]*v[(b*NN+j)*HH+lt];
    part[hg][lt]=p;
  }
  __syncthreads();
  if (tid < 128) sc[tid] = (part[0][tid]+part[1][tid])+(part[2][tid]+part[3][tid]);
  __syncthreads();
  {
    float p = (hg==0)? outb[lt] : 0.f;
    for (int m=hg*32; m<hg*32+32; m++) p += sc[m]*outWT[m*128+lt];
    part[hg][lt]=p;
  }
  __syncthreads();
  if (tid < 128){
    float x = eig[row*HH+tid] + ((part[0][tid]+part[1][tid])+(part[2][tid]+part[3][tid]));
    sx[tid] = x; sbuf[tid] = x;
  }
  __syncthreads();
  for (int s2=64;s2>0;s2>>=1){ if(tid<s2) sbuf[tid]+=sbuf[tid+s2]; __syncthreads(); }
  float mean = sbuf[0]*(1.f/128.f); __syncthreads();
  if (tid < 128){ float d = sx[tid]-mean; sbuf[tid]=d*d; }
  __syncthreads();
  for (int s2=64;s2>0;s2>>=1){ if(tid<s2) sbuf[tid]+=sbuf[tid+s2]; __syncthreads(); }
  float var = sbuf[0]*(1.f/128.f);
  if (tid < 128){
    float d = sx[tid]-mean;
    sxm[tid] = d*rsqrtf(var+EPSV)*fng[tid]+fnb[tid];
  }
  __syncthreads();
  {
    float p = (hg==0)? b1[lt] : 0.f;
    for (int m=hg*32; m<hg*32+32; m++) p += sxm[m]*w1T[m*128+lt];
    part[hg][lt]=p;
  }
  __syncthreads();
  if (tid < 128) stt[tid]=gelu_f((part[0][tid]+part[1][tid])+(part[2][tid]+part[3][tid]));
  __syncthreads();
  {
    float p = (hg==0)? b2[lt] : 0.f;
    for (int m=hg*32; m<hg*32+32; m++) p += stt[m]*w2T[m*128+lt];
    part[hg][lt]=p;
  }
  __syncthreads();
  if (tid < 128) sx[tid] = sx[tid] + ((part[0][tid]+part[1][tid])+(part[2][tid]+part[3][tid]));
  __syncthreads();
  if (tid < 4){
    float acc = db[tid];
    const float* wr = dW + tid*HH;
    for (int h2=0;h2<HH;h2++) acc += sx[h2]*wr[h2];
    int idx=(b*NHD+tid)*NN+qi;
    newe[idx]=acc; outp[8+idx]=acc;
  }
}

// ---------------- k_bx: xwl2-0 (blocks 0..15) ∪ fe2 (blocks 16..1039) — R14-proven ----
__global__ __launch_bounds__(512) void k_bx(const float* __restrict__ u,
    const float* __restrict__ newe,
    const float* __restrict__ w1g, const float* __restrict__ b1g,
    const ushortt* __restrict__ w2bf, const float* __restrict__ b2g,
    const int* __restrict__ length,
    bf16* __restrict__ bases,
    const float* __restrict__ xf0, const ushortt* __restrict__ wbfl0,
    float* __restrict__ xfW){
  int blk = blockIdx.x;
  int tid = threadIdx.x;
  __shared__ alignas(16) char us[38400];
  if (blk < 16){
    // ---- xwl2 layer 0: two 256-thread halves, each one (b,rq) item ----
    int sub = tid >> 8, lt = tid & 255;
    int item = blk*2 + sub;
    int b = item >> 2, rq = item & 3;
    int lane = lt & 63, w = lt >> 6, quad = lane >> 4, l15 = lane & 15;
    ushortt* sA = (ushortt*)(us + sub*8704);    // [32][136] per half
    for (int idx = lt; idx < 1024; idx += 256){
      int r = idx >> 5, c = idx & 31;
      int gr = b*128 + rq*32 + r;
      float4 xv = ((const float4*)xf0)[gr*32 + c];
      ushort4 o;
      o.x=f2us(xv.x); o.y=f2us(xv.y); o.z=f2us(xv.z); o.w=f2us(xv.w);
      *(ushort4*)&sA[r*136 + c*4] = o;
    }
    __syncthreads();
    f32x4 acc[2][2];
    #pragma unroll
    for (int mt=0;mt<2;mt++)
      #pragma unroll
      for (int nt=0;nt<2;nt++) acc[mt][nt] = (f32x4){0.f,0.f,0.f,0.f};
    #pragma unroll
    for (int kk = 0; kk < 128; kk += 32){
      bf16x8 af[2], bfr[2];
      #pragma unroll
      for (int mt=0;mt<2;mt++) af[mt] = *(const bf16x8*)&sA[(mt*16+l15)*136 + kk + quad*8];
      #pragma unroll
      for (int nt=0;nt<2;nt++) bfr[nt] = *(const bf16x8*)&wbfl0[((w*2+nt)*16+l15)*128 + kk + quad*8];
      #pragma unroll
      for (int mt=0;mt<2;mt++)
        #pragma unroll
        for (int nt=0;nt<2;nt++)
          acc[mt][nt] = __builtin_amdgcn_mfma_f32_16x16x32_bf16(af[mt], bfr[nt], acc[mt][nt], 0, 0, 0);
    }
    #pragma unroll
    for (int mt=0;mt<2;mt++)
      #pragma unroll
      for (int nt=0;nt<2;nt++){
        int h = (w*2+nt)*16 + l15;
        #pragma unroll
        for (int reg=0;reg<4;reg++){
          int prr = rq*32 + mt*16 + quad*4 + reg;
          xfW[(b*128 + prr)*128 + h] = acc[mt][nt][reg];
        }
      }
    return;
  }
  // ---- fe2: one block per bi, 8 waves cover all 128 A-rows ----
  int bi = blk - 16;
  int b = bi >> 7;
  int nloc = bi & 127;
  int len = length[b];
  if (nloc >= len) return;
  int lane = tid & 63, w = tid >> 6, quad = lane >> 4, l15 = lane & 15;
  int pr = w*16 + l15;
  ushortt* sW2 = (ushortt*)us;                  // 32768B; reused as sT (two passes)
  float* w1a = (float*)(us + 32768);            // 2048B
  float* w1b = (float*)(us + 34816);            // 1024B
  float* b2s = (float*)(us + 35840);            // 512B
  float* cn  = (float*)(us + 36352);            // [4][128] = 2048B
  for (int idx = tid; idx < 2048; idx += 512){
    int r = idx >> 4, cb = idx & 15;
    *(uint4*)&sW2[r*128 + ((cb*8) ^ ((r&15)<<3))] = *(const uint4*)&w2bf[r*128 + cb*8];
  }
  if (tid < 128){
    w1a[tid*4+0] = b1g[tid];
    w1a[tid*4+1] = w1g[tid*5+0];
    w1a[tid*4+2] = w1g[tid*5+1];
    w1a[tid*4+3] = w1g[tid*5+2];
    w1b[tid*2+0] = w1g[tid*5+3];
    w1b[tid*2+1] = w1g[tid*5+4];
    b2s[tid] = b2g[tid];
  }
  if (tid < 512){
    int k = tid >> 7, m = tid & 127;
    cn[k*128+m] = u[(b*NN+nloc)*NN + m] * newe[(b*NHD+k)*NN + m];
  }
  __syncthreads();
  bool wact = (w*16) < len;     // rows >= len in active waves are computed but never stored
  f32x4 acc[8];
  #pragma unroll
  for (int nt=0;nt<8;nt++) acc[nt] = (f32x4){0.f,0.f,0.f,0.f};
  if (wact){
    float f0=0.f, f1=0.f, f2v=0.f, f3=0.f;
    const float4* ur = (const float4*)(u + ((size_t)b*NN + pr)*NN);
    for (int m4 = quad*8; m4 < quad*8+8; m4++){
      float4 uv = ur[m4];
      int m = m4*4;
      f0 += cn[m]*uv.x; f0 += cn[m+1]*uv.y; f0 += cn[m+2]*uv.z; f0 += cn[m+3]*uv.w;
      f1 += cn[128+m]*uv.x; f1 += cn[128+m+1]*uv.y; f1 += cn[128+m+2]*uv.z; f1 += cn[128+m+3]*uv.w;
      f2v += cn[256+m]*uv.x; f2v += cn[256+m+1]*uv.y; f2v += cn[256+m+2]*uv.z; f2v += cn[256+m+3]*uv.w;
      f3 += cn[384+m]*uv.x; f3 += cn[384+m+1]*uv.y; f3 += cn[384+m+2]*uv.z; f3 += cn[384+m+3]*uv.w;
    }
    f0 += __shfl_xor(f0, 16, 64);  f0 += __shfl_xor(f0, 32, 64);
    f1 += __shfl_xor(f1, 16, 64);  f1 += __shfl_xor(f1, 32, 64);
    f2v += __shfl_xor(f2v, 16, 64); f2v += __shfl_xor(f2v, 32, 64);
    f3 += __shfl_xor(f3, 16, 64);  f3 += __shfl_xor(f3, 32, 64);
    float dg = (pr == nloc) ? 1.0f : 0.0f;
    for (int kk = 0; kk < 128; kk += 32){
      bf16x8 af;
      #pragma unroll
      for (int j=0;j<8;j++){
        int m = kk + quad*8 + j;
        const float4 wa = *(const float4*)&w1a[m*4];
        const float2 wb = *(const float2*)&w1b[m*2];
        float a = wa.x + wa.y*dg + wa.z*f0 + wa.w*f1 + wb.x*f2v + wb.y*f3;
        af[j] = (short)f2us(gelu_fe(a));
      }
      #pragma unroll
      for (int nt=0;nt<8;nt++){
        int rowb = nt*16 + l15;
        int off = (kk + quad*8) ^ (l15 << 3);   // ushort units; rowb&15 == l15
        bf16x8 bfr = *(const bf16x8*)&sW2[rowb*128 + off];
        acc[nt] = __builtin_amdgcn_mfma_f32_16x16x32_bf16(af, bfr, acc[nt], 0, 0, 0);
      }
    }
  }
  __syncthreads();              // all sW2 MFMA reads done -> reuse as sT
  ushortt* sT = sW2;            // [64][132] per pass
  // pass 1: rows 0..63 (waves 0..3)
  if (wact && w < 4){
    #pragma unroll
    for (int nt=0;nt<8;nt++){
      int h = nt*16 + l15;
      float bb = b2s[h];
      #pragma unroll
      for (int reg=0;reg<4;reg++){
        int lr = w*16 + quad*4 + reg;
        sT[lr*132 + h] = f2us(gelu_fe(acc[nt][reg] + bb));
      }
    }
  }
  __syncthreads();
  {
    int rmax = len < 64 ? len : 64;
    ushort4* gout = (ushort4*)(bases + (size_t)bi*16384);
    for (int idx = tid; idx < rmax*32; idx += 512){
      int row = idx >> 5, seg = idx & 31;
      gout[idx] = *(const ushort4*)&sT[row*132 + seg*4];
    }
  }
  __syncthreads();
  // pass 2: rows 64..127 (waves 4..7)
  if (wact && w >= 4){
    #pragma unroll
    for (int nt=0;nt<8;nt++){
      int h = nt*16 + l15;
      float bb = b2s[h];
      #pragma unroll
      for (int reg=0;reg<4;reg++){
        int lr = (w-4)*16 + quad*4 + reg;
        sT[lr*132 + h] = f2us(gelu_fe(acc[nt][reg] + bb));
      }
    }
  }
  __syncthreads();
  {
    int rmax2 = len - 64; if (rmax2 < 0) rmax2 = 0; if (rmax2 > 64) rmax2 = 64;
    if (rmax2 > 0){
      ushort4* gout = (ushort4*)(bases + (size_t)bi*16384 + 64*128);
      for (int idx = tid; idx < rmax2*32; idx += 512){
        int row = idx >> 5, seg = idx & 31;
        gout[idx] = *(const ushort4*)&sT[row*132 + seg*4];
      }
    }
  }
}

// ---------------- message passing ----------------
// gs layout per layer (stride 2560): [bank0..7][sum1(128)|sq1(128)] + 2048:[sum2|sq2]

// xwl2: 64 blocks, 16 rows each; dead slabs return early (R16-proven).
__global__ __launch_bounds__(256) void k_xwl2(const float* __restrict__ xfprev,
    const float* __restrict__ t2, const float* __restrict__ gsum2p,
    const float* __restrict__ gsq2p, const float* __restrict__ g2p,
    const float* __restrict__ bb2p, const int* __restrict__ length,
    const ushortt* __restrict__ wbfl, float* __restrict__ xfB,
    float* __restrict__ xfW){
  int blk = blockIdx.x;
  int b = blk >> 3, r16 = blk & 7;
  if (r16*16 >= length[b]) return;   // dead 16-row slab: outputs never read
  int tid = threadIdx.x;
  int lane = tid & 63, w = tid >> 6, quad = lane >> 4, l15 = lane & 15;
  __shared__ alignas(16) ushortt sA[16*136];
  __shared__ float smu[128], sistd[128], sg[128], sbb[128];
  if (tid < 128){
    float cnt = 0.f;
    for (int q2=0;q2<BB;q2++) cnt += (float)length[q2];
    float mu = gsum2p[tid]/cnt;
    float var = gsq2p[tid]/cnt - mu*mu;
    smu[tid]=mu; sistd[tid]=rsqrtf(fmaxf(var,0.0f)+EPSV);
    sg[tid]=g2p[tid]; sbb[tid]=bb2p[tid];
  }
  __syncthreads();
  for (int idx = tid; idx < 512; idx += 256){
    int r = idx >> 5, c = idx & 31;
    int gr = b*128 + r16*16 + r;
    float4 xv = ((const float4*)xfprev)[gr*32 + c];
    float4 tv = ((const float4*)t2)[gr*32 + c];
    int f0 = c*4;
    xv.x += fmaxf((tv.x-smu[f0+0])*sistd[f0+0]*sg[f0+0]+sbb[f0+0], 0.f);
    xv.y += fmaxf((tv.y-smu[f0+1])*sistd[f0+1]*sg[f0+1]+sbb[f0+1], 0.f);
    xv.z += fmaxf((tv.z-smu[f0+2])*sistd[f0+2]*sg[f0+2]+sbb[f0+2], 0.f);
    xv.w += fmaxf((tv.w-smu[f0+3])*sistd[f0+3]*sg[f0+3]+sbb[f0+3], 0.f);
    ((float4*)xfB)[gr*32 + c] = xv;
    ushort4 o;
    o.x=f2us(xv.x); o.y=f2us(xv.y); o.z=f2us(xv.z); o.w=f2us(xv.w);
    *(ushort4*)&sA[r*136 + c*4] = o;
  }
  __syncthreads();
  f32x4 acc[2];
  #pragma unroll
  for (int nt=0;nt<2;nt++) acc[nt] = (f32x4){0.f,0.f,0.f,0.f};
  #pragma unroll
  for (int kk = 0; kk < 128; kk += 32){
    bf16x8 af = *(const bf16x8*)&sA[l15*136 + kk + quad*8];
    #pragma unroll
    for (int nt=0;nt<2;nt++){
      bf16x8 bfr = *(const bf16x8*)&wbfl[((w*2+nt)*16+l15)*128 + kk + quad*8];
      acc[nt] = __builtin_amdgcn_mfma_f32_16x16x32_bf16(af, bfr, acc[nt], 0, 0, 0);
    }
  }
  #pragma unroll
  for (int nt=0;nt<2;nt++){
    int h = (w*2+nt)*16 + l15;
    #pragma unroll
    for (int reg=0;reg<4;reg++){
      int prr = r16*16 + quad*4 + reg;
      xfW[(b*128 + prr)*128 + h] = acc[nt][reg];
    }
  }
}

// per-edge elementwise + FUSED g1 GEMM + BN1 partial stats (R16-proven, len-masked)
__global__ __launch_bounds__(512) void k_edge(const float* __restrict__ xfin, float* __restrict__ xfout,
    const bf16* __restrict__ bases, const float* __restrict__ xfW,
    const float* __restrict__ bondWl, const int* __restrict__ ef,
    const int* __restrict__ length,
    const float* __restrict__ w1t, const float* __restrict__ bias1,
    float* __restrict__ t1, float* __restrict__ gst){
  int bj = blockIdx.x; int b = bj >> 7, j = bj & 127;
  int len = length[b];
  if (j >= len) return;               // dead row: outputs never read
  int tid = threadIdx.x;
  int is = tid >> 6, hp = tid & 63;   // i-slice 0..7, h-pair 0..63
  int h2 = hp*2;
  __shared__ float sBW[10][128];
  __shared__ int sEf[128];
  __shared__ float part[8][128];
  for (int idx = tid; idx < 1280; idx += 512) sBW[idx>>7][idx&127] = bondWl[idx];
  if (tid < 128) sEf[tid] = ef[(b*NN + tid)*NN + j];
  __syncthreads();
  float a0 = 0.f, a1 = 0.f;
  {
    const float* xwb = xfW + b*NN*HH;
    const ushortt* bb = (const ushortt*)(bases + ((size_t)b*NN + j)*NN*HH);
    for (int i = is; i < len; i += 8){
      int ev = sEf[i];
      float2 xw = *(const float2*)&xwb[i*128 + h2];
      float2 bw = *(const float2*)&sBW[ev][h2];
      unsigned bv = *(const unsigned*)&bb[i*128 + h2];
      float v0 = gelu_h(xw.x + bw.x);
      float v1 = gelu_h(xw.y + bw.y);
      a0 += v0 * us2f((ushortt)(bv & 0xffffu));
      a1 += v1 * us2f((ushortt)(bv >> 16));
    }
  }
  part[is][h2] = a0; part[is][h2+1] = a1;
  __syncthreads();
  if (tid < 128){
    int o = (b*NN + j)*HH + tid;
    float xrow = xfin[o]
      + ((part[0][tid]+part[1][tid])+(part[2][tid]+part[3][tid]))
      + ((part[4][tid]+part[5][tid])+(part[6][tid]+part[7][tid]));
    xfout[o] = xrow;
    part[0][tid] = xrow;      // own-column read->write, no race
  }
  __syncthreads();
  // g1 GEMM on the row + BN1 partial stats
  int h = tid & 127, ih = tid >> 7;
  float acc = (ih==0) ? bias1[h] : 0.f;
  {
    const float* wcol = w1t + h;
    int m0 = ih*32;
    for (int m = m0; m < m0+32; m++) acc += part[0][m]*wcol[m*128];
  }
  float* red = &sBW[0][0];
  __syncthreads();
  red[ih*128 + h] = acc; __syncthreads();
  if (tid < 128){
    float t1v = red[tid] + red[128+tid] + red[256+tid] + red[384+tid];
    t1[(b*NN + j)*HH + tid] = t1v;
    int bank = bj & 7;
    atomicAdd(&gst[bank*256 + tid], t1v);
    atomicAdd(&gst[bank*256 + 128 + tid], t1v*t1v);
  }
}

// finalize BN1 (sum 8 banks) + relu + g2 GEMM + partial BN2 stats (R17-proven)
__global__ __launch_bounds__(512) void k_g2s(const float* __restrict__ t1,
    const float* __restrict__ gstL,
    const float* __restrict__ g1, const float* __restrict__ bb1,
    const float* __restrict__ w2t, const float* __restrict__ bias2,
    const int* __restrict__ length, float* __restrict__ t2){
  int blk = blockIdx.x; int tid = threadIdx.x;
  int r0 = blk*4;
  {
    int b0 = r0 >> 7, n0 = r0 & 127;
    if (n0 >= length[b0]) return;    // whole 4-row group dead (groups never cross b)
  }
  int f = tid & 127, rh = tid >> 7;   // rh 0..3
  __shared__ float sy[4][128];
  __shared__ float red1[4][128], red2[4][128];
  float cnt = 0.f;
  for (int b=0;b<BB;b++) cnt += (float)length[b];
  float su = 0.f, sq = 0.f;
  #pragma unroll
  for (int k=0;k<8;k++){ su += gstL[k*256 + f]; sq += gstL[k*256 + 128 + f]; }
  float mu = su/cnt;
  float var = sq/cnt - mu*mu;
  float istd = rsqrtf(fmaxf(var,0.0f)+EPSV);
  float gg = g1[f], bbv = bb1[f];
  int rg = r0 + rh; int b = rg >> 7, n = rg & 127;
  bool live = (n < length[b]);
  if (live){
    float x = t1[rg*128 + f];
    float y = (x-mu)*istd*gg + bbv;
    sy[rh][f] = fmaxf(y, 0.0f);
  }
  __syncthreads();
  float s = 0.f, s2 = 0.f;
  if (live){
    float acc = bias2[f];
    for (int m=0;m<128;m++) acc += sy[rh][m]*w2t[m*128+f];
    t2[rg*128+f] = acc;
    s = acc; s2 = acc*acc;
  }
  red1[rh][f]=s; red2[rh][f]=s2; __syncthreads();
  if (tid < 128){
    atomicAdd((float*)&gstL[2048 + tid], (red1[0][tid]+red1[1][tid])+(red1[2][tid]+red1[3][tid]));
    atomicAdd((float*)&gstL[2048 + 128 + tid], (red2[0][tid]+red2[1][tid])+(red2[2][tid]+red2[3][tid]));
  }
}

// final BN2-apply fused into pooling + linear head (R17-proven, 512 thr)
__global__ __launch_bounds__(512) void k_pool2(const float* __restrict__ xf, const float* __restrict__ t2,
                        const float* __restrict__ gsum2, const float* __restrict__ gsq2,
                        const float* __restrict__ g2, const float* __restrict__ bb2,
                        const int* __restrict__ length,
                        const float* lw, const float* lb, float* __restrict__ outp){
  int b = blockIdx.x, tid=threadIdx.x;
  int h = tid & 127, slice = tid >> 7;
  int len = length[b];
  float cnt = 0.f;
  for (int q2=0;q2<BB;q2++) cnt += (float)length[q2];
  float mu = gsum2[h]/cnt;
  float var = gsq2[h]/cnt - mu*mu;
  float istd = rsqrtf(fmaxf(var,0.0f)+EPSV);
  float gg = g2[h], bbv = bb2[h];
  float s=0.f;
  for (int n2=slice; n2<len; n2+=4){
    int o = (b*NN+n2)*HH+h;
    float x = xf[o] + fmaxf((t2[o]-mu)*istd*gg+bbv, 0.0f);
    s += x;
  }
  __shared__ float part[4][128];
  __shared__ float red[128];
  part[slice][h] = s; __syncthreads();
  if (tid < 128){
    float ss = (part[0][tid]+part[1][tid])+(part[2][tid]+part[3][tid]);
    ss /= (float)len;
    red[tid] = ss*lw[tid];
  }
  __syncthreads();
  for (int st=64;st>0;st>>=1){ if(tid<st) red[tid]+=red[tid+st]; __syncthreads(); }
  if (tid==0) outp[b]=red[0]+lb[0];
}

// ---------------- host ----------------

extern "C" void kernel_launch(void* const* d_in, const int* in_sizes, int n_in,
                              void* d_out, int out_size, void* d_ws, size_t ws_size,
                              hipStream_t stream) {
  (void)in_sizes; (void)n_in; (void)out_size; (void)ws_size;
  const float* e        = (const float*)d_in[0];
  const float* u        = (const float*)d_in[1];
  const float* atom_emb = (const float*)d_in[2];
  const float* bond_emb = (const float*)d_in[3];
  const float* eigw_W   = (const float*)d_in[4];
  const float* eigw_b   = (const float*)d_in[5];
  const float* mng      = (const float*)d_in[6];
  const float* mnb      = (const float*)d_in[7];
  const float* qkvW     = (const float*)d_in[8];
  const float* qkvb     = (const float*)d_in[9];
  const float* outW     = (const float*)d_in[10];
  const float* outb     = (const float*)d_in[11];
  const float* fng      = (const float*)d_in[12];
  const float* fnb      = (const float*)d_in[13];
  const float* ffn1W    = (const float*)d_in[14];
  const float* ffn1b    = (const float*)d_in[15];
  const float* ffn2W    = (const float*)d_in[16];
  const float* ffn2b    = (const float*)d_in[17];
  const float* decW     = (const float*)d_in[18];
  const float* decb     = (const float*)d_in[19];
  const float* fe1W     = (const float*)d_in[20];
  const float* fe1b     = (const float*)d_in[21];
  const float* fe2W     = (const float*)d_in[22];
  const float* fe2b     = (const float*)d_in[23];
  const float* preW     = (const float*)d_in[24];
  const float* preb     = (const float*)d_in[25];
  const float* f1W      = (const float*)d_in[26];
  const float* f1b      = (const float*)d_in[27];
  const float* bn1g     = (const float*)d_in[28];
  const float* bn1b     = (const float*)d_in[29];
  const float* f2W      = (const float*)d_in[30];
  const float* f2b      = (const float*)d_in[31];
  const float* bn2g     = (const float*)d_in[32];
  const float* bn2b     = (const float*)d_in[33];
  const float* linW     = (const float*)d_in[34];
  const float* linb     = (const float*)d_in[35];
  const int* nodef      = (const int*)d_in[36];
  const int* edgef      = (const int*)d_in[37];
  const int* length     = (const int*)d_in[38];

  float* outp = (float*)d_out;   // h[8] ++ new_e[4096] ++ attn[524288], f32

  char* p = (char*)d_ws;
  auto alloc = [&](size_t bytes)->void*{ void* r=(void*)p; p += (bytes+255)&~(size_t)255; return r; };
  const int TOK = BB*NN*HH;           // 131072
  float* eig   = (float*)alloc(TOK*4);
  float* q     = (float*)alloc(TOK*4);
  float* kT    = (float*)alloc(TOK*4);
  float* v     = (float*)alloc(TOK*4);
  float* newe  = (float*)alloc(BB*NHD*NN*4);
  bf16*  bases = (bf16*) alloc((size_t)BB*NN*NN*HH*2);
  float* xf0   = (float*)alloc(TOK*4);
  float* xfB   = (float*)alloc(TOK*4);
  float* xfC   = (float*)alloc(TOK*4);
  float* xfD   = (float*)alloc(TOK*4);
  float* t1    = (float*)alloc(TOK*4);
  float* t2    = (float*)alloc(TOK*4);
  float* xfW   = (float*)alloc(TOK*4);
  float* gs    = (float*)alloc(10240*4);         // 4 layers x 2560
  ushortt* wbf = (ushortt*)alloc(81920*2);
  float* eigWT = (float*)alloc(16512*4);
  float* qkvWT = (float*)alloc(49152*4);
  float* outWT = (float*)alloc(16384*4);
  float* ffn1WT= (float*)alloc(16384*4);
  float* ffn2WT= (float*)alloc(16384*4);
  float* f1WT  = (float*)alloc(65536*4);
  float* f2WT  = (float*)alloc(65536*4);
  float* bondWall = (float*)alloc(5120*4);

  k_prep<<<512, 256, 0, stream>>>(fe2W, preW, eigw_W, qkvW, outW, ffn1W, ffn2W,
                                  f1W, f2W, atom_emb, nodef, bond_emb, preb,
                                  wbf, gs, xf0, eigWT, qkvWT, outWT, ffn1WT,
                                  ffn2WT, f1WT, f2WT, bondWall);

  k_fe_a<<<BB*NN, 128, 0, stream>>>(e, eigWT, eigw_b, mng, mnb, qkvWT, qkvb, eig, q, kT, v);

  k_attc<<<BB*NN, 512, 0, stream>>>(q, kT, v, eig, length,
                                    outWT, outb, fng, fnb,
                                    ffn1WT, ffn1b, ffn2WT, ffn2b,
                                    decW, decb, newe, outp);

  // xwl2-0 (blocks 0..15) + bases fe2 (blocks 16..1039, one per bi)
  k_bx<<<16 + BB*NN, 512, 0, stream>>>(u, newe, fe1W, fe1b, wbf, fe2b, length,
                                       bases, xf0, wbf + 16384, xfW);

  // message passing
  const float* xfprev = xf0;
  float* xfcur = xfC;
  for (int l=0;l<LAY;l++){
    const ushortt* wbfl = wbf + 16384 + l*16384;
    float* gsl = gs + l*2560;
    float* gsp = gs + (l-1)*2560;
    if (l > 0){
      k_xwl2<<<BB*8, 256, 0, stream>>>(xfprev, t2, gsp+2048, gsp+2048+128,
                                       bn2g + (l-1)*HH, bn2b + (l-1)*HH,
                                       length, wbfl, xfB, xfW);
    }
    const float* xin = (l==0)? xf0 : xfB;
    k_edge<<<BB*NN, 512, 0, stream>>>(xin, xfcur, bases, xfW, bondWall + l*1280,
                                      edgef, length,
                                      f1WT + l*16384, f1b + l*HH, t1, gsl);
    k_g2s<<<256, 512, 0, stream>>>(t1, gsl, bn1g + l*HH, bn1b + l*HH,
                                   f2WT + l*16384, f2b + l*HH, length, t2);
    xfprev = xfcur;
    xfcur = (xfcur == xfC) ? xfD : xfC;
  }
  // final: BN2(layer3) applied inside pool (xfprev holds layer-3 output)
  k_pool2<<<BB, 512, 0, stream>>>(xfprev, t2, gs+3*2560+2048, gs+3*2560+2048+128,
                                  bn2g + 3*HH, bn2b + 3*HH, length, linW, linb, outp);
}